// Round 18
// baseline (461.937 us; speedup 1.0000x reference)
//
#include <hip/hip_runtime.h>
#include <cstdint>
#include <cstddef>

typedef __bf16 bf16_t;
typedef __bf16 bf16x8 __attribute__((ext_vector_type(8)));
typedef __bf16 bf16x4 __attribute__((ext_vector_type(4)));
typedef float  f32x4  __attribute__((ext_vector_type(4)));

#define MFMA(a, b, c) __builtin_amdgcn_mfma_f32_16x16x32_bf16((a), (b), (c), 0, 0, 0)

// async global->LDS, 16B/lane; dest = wave-uniform base + lane*16 (linear)
__device__ __forceinline__ void gload16(const bf16_t* g, bf16_t* l) {
  __builtin_amdgcn_global_load_lds(
      (const __attribute__((address_space(1))) void*)g,
      (__attribute__((address_space(3))) void*)l, 16, 0, 0);
}

// BS=64, S=128, DM=512, H=8, PRED=96, NF=65536

// ---------------------------------------------------------------- converts
__global__ __launch_bounds__(256) void k_convert_dual(const float* __restrict__ in,
                                                      bf16_t* __restrict__ xb,
                                                      bf16_t* __restrict__ xT) {
  __shared__ bf16_t tile[32][34];
  int tx = threadIdx.x & 31, ty = threadIdx.x >> 5;
  int c0 = blockIdx.x * 32, r0 = blockIdx.y * 32;
#pragma unroll
  for (int j = 0; j < 4; ++j) {
    int r = r0 + ty + j * 8;
    bf16_t bv = (bf16_t)in[(size_t)r * 512 + c0 + tx];
    xb[(size_t)r * 512 + c0 + tx] = bv;
    tile[ty + j * 8][tx] = bv;
  }
  __syncthreads();
  int b = (r0 + tx) >> 7, s = (r0 + tx) & 127;
#pragma unroll
  for (int j = 0; j < 4; ++j) {
    int i = c0 + ty + j * 8;
    xT[(size_t)b * 65536 + (size_t)i * 128 + s] = tile[tx][ty + j * 8];
  }
}

// ---------------------------------------------------------------- weight products
template <int BMODE>
__global__ __launch_bounds__(256) void k_wprod(const float* __restrict__ Ap,
                                               const float* __restrict__ Bp,
                                               bf16_t* __restrict__ out,
                                               int ldA, int ldB) {
  __shared__ __align__(16) bf16_t S[128 * 68 * 2];
  bf16_t* As = S;
  bf16_t* Bs = S + 128 * 68;
  const int tid = threadIdx.x, lane = tid & 63, wave = tid >> 6;
  const int wr = (wave >> 1) * 64, wc = (wave & 1) * 64;
  const int lr = lane & 15, lk = (lane >> 4) * 8, frow = (lane >> 4) * 4;
  const int m0 = blockIdx.x * 128, n0 = blockIdx.y * 128, h = blockIdx.z;
  const int sr = tid >> 3, sc = (tid & 7) * 8;
  f32x4 acc[4][4] = {};

  for (int kt = 0; kt < 512; kt += 64) {
#pragma unroll
    for (int rr = 0; rr < 4; ++rr) {
      int r = sr + 32 * rr;
      const float* ap = Ap + (size_t)(m0 + r) * ldA + h * 512 + kt + sc;
      bf16x8 av;
#pragma unroll
      for (int e = 0; e < 8; ++e) av[e] = (bf16_t)ap[e];
      *(bf16x8*)(As + r * 68 + sc) = av;
    }
    if (BMODE == 0) {
#pragma unroll
      for (int rr = 0; rr < 4; ++rr) {
        int r = sr + 32 * rr;
        const float* bp = Bp + (size_t)(n0 + r) * ldB + h * 512 + kt + sc;
        bf16x8 bv;
#pragma unroll
        for (int e = 0; e < 8; ++e) bv[e] = (bf16_t)bp[e];
        *(bf16x8*)(Bs + r * 68 + sc) = bv;
      }
    } else {
#pragma unroll
      for (int rr = 0; rr < 8; ++rr) {
        int kr = (tid >> 5) + 8 * rr;
        int nc = (tid & 31) * 4;
        const float* bp = Bp + (size_t)(h * 512 + kt + kr) * ldB + n0 + nc;
        float4 v = *(const float4*)bp;
        Bs[(nc + 0) * 68 + kr] = (bf16_t)v.x;
        Bs[(nc + 1) * 68 + kr] = (bf16_t)v.y;
        Bs[(nc + 2) * 68 + kr] = (bf16_t)v.z;
        Bs[(nc + 3) * 68 + kr] = (bf16_t)v.w;
      }
    }
    __syncthreads();
#pragma unroll
    for (int kk = 0; kk < 2; ++kk) {
      bf16x8 af[4], bfr[4];
#pragma unroll
      for (int i = 0; i < 4; ++i)
        af[i] = *(const bf16x8*)(As + (wr + i * 16 + lr) * 68 + kk * 32 + lk);
#pragma unroll
      for (int j = 0; j < 4; ++j)
        bfr[j] = *(const bf16x8*)(Bs + (wc + j * 16 + lr) * 68 + kk * 32 + lk);
#pragma unroll
      for (int i = 0; i < 4; ++i)
#pragma unroll
        for (int j = 0; j < 4; ++j)
          acc[i][j] = MFMA(af[i], bfr[j], acc[i][j]);
    }
    __syncthreads();
  }

  bf16_t* Full = S;  // [128 n][136 m]
#pragma unroll
  for (int i = 0; i < 4; ++i)
#pragma unroll
    for (int j = 0; j < 4; ++j)
#pragma unroll
      for (int q = 0; q < 4; ++q)
        Full[(wc + j * 16 + lr) * 136 + wr + i * 16 + frow + q] = (bf16_t)acc[i][j][q];
  __syncthreads();
#pragma unroll
  for (int it = 0; it < 8; ++it) {
    int r = it * 16 + (tid >> 4);
    int c = (tid & 15) * 8;
    *(bf16x8*)(out + ((size_t)(h * 512 + n0 + r)) * 512 + m0 + c) =
        *(const bf16x8*)(Full + r * 136 + c);
  }
}

// ---------------------------------------------------------------- bias helpers
__global__ __launch_bounds__(256) void k_sbias2(const float* __restrict__ Wq,
                                                const float* __restrict__ bk,
                                                const float* __restrict__ Wk,
                                                const float* __restrict__ bq,
                                                bf16_t* __restrict__ W12b,
                                                float* __restrict__ c) {
  const int lane = threadIdx.x & 63, wave = threadIdx.x >> 6;
  const int i = blockIdx.x * 4 + wave;
  for (int h = 0; h < 8; ++h) {
    float s1 = 0.f, s2 = 0.f;
    for (int d = lane; d < 512; d += 64) {
      s1 += Wq[(size_t)i * 4096 + h * 512 + d] * bk[h * 512 + d];
      s2 += Wk[(size_t)i * 4096 + h * 512 + d] * bq[h * 512 + d];
    }
#pragma unroll
    for (int o = 32; o > 0; o >>= 1) { s1 += __shfl_down(s1, o); s2 += __shfl_down(s2, o); }
    if (lane == 0) {
      W12b[h * 512 + i] = (bf16_t)s1;
      W12b[(8 + h) * 512 + i] = (bf16_t)s2;
    }
  }
  if (blockIdx.x == 0 && wave == 0) {
    for (int h = 0; h < 8; ++h) {
      float cc = 0.f;
      for (int d = lane; d < 512; d += 64) cc += bq[h * 512 + d] * bk[h * 512 + d];
#pragma unroll
      for (int o = 32; o > 0; o >>= 1) cc += __shfl_down(cc, o);
      if (lane == 0) c[h] = cc;
    }
  }
}

// TallT[16][8192] f32 = x @ W12^T (+cb for c<8), MFMA
__global__ __launch_bounds__(256) void k_tbias2(const bf16_t* __restrict__ xb,
                                                const bf16_t* __restrict__ W12b,
                                                const float* __restrict__ cb,
                                                float* __restrict__ TallT) {
  __shared__ __align__(16) bf16_t Ws[16 * 516];
  const int tid = threadIdx.x, lane = tid & 63, wave = tid >> 6;
  const int lr = lane & 15, lk = (lane >> 4) * 8, frow = (lane >> 4) * 4;
  for (int i = tid; i < 1024; i += 256) {
    int r = i >> 6, ccol = (i & 63) * 8;
    *(bf16x8*)(Ws + r * 516 + ccol) = *(const bf16x8*)(W12b + r * 512 + ccol);
  }
  __syncthreads();
  const int row0 = blockIdx.x * 64 + wave * 16;
  const bf16_t* xr = xb + (size_t)(row0 + lr) * 512 + lk;
  f32x4 acc = {};
#pragma unroll
  for (int kx = 0; kx < 16; ++kx) {
    bf16x8 af = *(const bf16x8*)(xr + kx * 32);
    bf16x8 bfv = *(const bf16x8*)(Ws + lr * 516 + kx * 32 + lk);
    acc = MFMA(af, bfv, acc);
  }
#pragma unroll
  for (int q = 0; q < 4; ++q) {
    int r = row0 + frow + q;
    float v = acc[q] + (lr < 8 ? cb[lr] : 0.f);
    TallT[(size_t)lr * 8192 + r] = v;
  }
}

// cvec = bv @ Wo + bo, 2-stage
__global__ __launch_bounds__(256) void k_cvec1(const float* __restrict__ bv,
                                               const float* __restrict__ Wo,
                                               float* __restrict__ cpart) {
  int cch = blockIdx.x, d = threadIdx.x * 2;
  float ax = 0.f, ay = 0.f;
  for (int n = cch * 128; n < cch * 128 + 128; ++n) {
    float b = bv[n];
    float2 w = *(const float2*)(Wo + (size_t)n * 512 + d);
    ax += b * w.x; ay += b * w.y;
  }
  cpart[(size_t)cch * 512 + d] = ax;
  cpart[(size_t)cch * 512 + d + 1] = ay;
}
__global__ __launch_bounds__(256) void k_cvec2(const float* __restrict__ cpart,
                                               const float* __restrict__ bo,
                                               float* __restrict__ cvec) {
  int d = blockIdx.x * 256 + threadIdx.x;
  float s = bo[d];
  for (int cch = 0; cch < 32; ++cch) s += cpart[(size_t)cch * 512 + d];
  cvec[d] = s;
}

// ---------------------------------------------------------------- attention core
// k_attn9 (best measured: 73 us). 1-wave blocks, grid 2048, batched direct loads.
__global__ __launch_bounds__(64, 2) void k_attn9(const bf16_t* __restrict__ xb,
                                                 const bf16_t* __restrict__ xT,
                                                 bf16_t* __restrict__ TU,
                                                 const float* __restrict__ prev,
                                                 const float* __restrict__ scale_p,
                                                 const float* __restrict__ TallT,
                                                 int hg) {
  __shared__ __align__(16) bf16_t Pl[16 * 136];
  __shared__ __align__(16) bf16_t Bw[16 * 72];

  const int lane = threadIdx.x;
  const int lr = lane & 15, lk = (lane >> 4) * 8, frow = (lane >> 4) * 4;
  const int bid = blockIdx.x;
  const int bx = (bid & 7) * 256 + (bid >> 3);
  const int b = bx >> 5, hp = (bx >> 3) & 3, rg = bx & 7;
  const int h = hg * 4 + hp;
  const int r0 = rg * 16;
  const bf16_t* xB = xb + (size_t)b * 65536;
  const bf16_t* xTB = xT + (size_t)b * 65536;
  bf16_t* tB = TU + ((size_t)hp * 8192 + b * 128 + r0) * 512;

  bf16x8 tf[16];
  const bf16_t* aP = tB + (size_t)lr * 512 + lk;
#pragma unroll
  for (int kx = 0; kx < 16; ++kx) tf[kx] = *(const bf16x8*)(aP + kx * 32);

  f32x4 sacc[8] = {};
  const bf16_t* bP = xB + (size_t)lr * 512 + lk;
#pragma unroll
  for (int kc = 0; kc < 8; ++kc) {
    bf16x8 bb0[8], bb1[8];
#pragma unroll
    for (int j = 0; j < 8; ++j)
      bb0[j] = *(const bf16x8*)(bP + (size_t)j * 8192 + (2 * kc) * 32);
#pragma unroll
    for (int j = 0; j < 8; ++j)
      bb1[j] = *(const bf16x8*)(bP + (size_t)j * 8192 + (2 * kc + 1) * 32);
    __builtin_amdgcn_s_setprio(1);
#pragma unroll
    for (int j = 0; j < 8; ++j) sacc[j] = MFMA(tf[2 * kc], bb0[j], sacc[j]);
#pragma unroll
    for (int j = 0; j < 8; ++j) sacc[j] = MFMA(tf[2 * kc + 1], bb1[j], sacc[j]);
    __builtin_amdgcn_s_setprio(0);
  }

  const float scl = scale_p[0];
  const float* t1p = TallT + h * 8192 + b * 128 + r0;
  const float* t2p = TallT + (8 + h) * 8192 + b * 128;
  float t2r[8];
#pragma unroll
  for (int j = 0; j < 8; ++j) t2r[j] = t2p[j * 16 + lr];
#pragma unroll
  for (int e = 0; e < 4; ++e) {
    const int rl = frow + e;
    const float t1 = t1p[rl];
    const float* prow = prev + (((size_t)(b * 8 + h)) * 128 + r0 + rl) * 128;
    float pv[8];
#pragma unroll
    for (int j = 0; j < 8; ++j) pv[j] = prow[j * 16 + lr];
    float mx = -3.4e38f;
#pragma unroll
    for (int j = 0; j < 8; ++j) {
      float v = scl * (sacc[j][e] + t1 + t2r[j]) + pv[j];
      sacc[j][e] = v;
      mx = fmaxf(mx, v);
    }
    mx = fmaxf(mx, __shfl_xor(mx, 1));
    mx = fmaxf(mx, __shfl_xor(mx, 2));
    mx = fmaxf(mx, __shfl_xor(mx, 4));
    mx = fmaxf(mx, __shfl_xor(mx, 8));
    float sum = 0.f;
#pragma unroll
    for (int j = 0; j < 8; ++j) {
      float p = __expf(sacc[j][e] - mx);
      sacc[j][e] = p;
      sum += p;
    }
    sum += __shfl_xor(sum, 1);
    sum += __shfl_xor(sum, 2);
    sum += __shfl_xor(sum, 4);
    sum += __shfl_xor(sum, 8);
    float inv = 1.f / sum;
#pragma unroll
    for (int j = 0; j < 8; ++j)
      Pl[rl * 136 + j * 16 + lr] = (bf16_t)(sacc[j][e] * inv);
  }

#pragma unroll
  for (int dc = 0; dc < 8; ++dc) {
    bf16x8 xf[16];
#pragma unroll
    for (int kk = 0; kk < 4; ++kk)
#pragma unroll
      for (int j = 0; j < 4; ++j)
        xf[kk * 4 + j] =
            *(const bf16x8*)(xTB + (size_t)(dc * 64 + j * 16 + lr) * 128 + kk * 32 + lk);
    f32x4 oacc[4] = {};
    __builtin_amdgcn_s_setprio(1);
#pragma unroll
    for (int kk = 0; kk < 4; ++kk) {
      bf16x8 pa = *(const bf16x8*)(Pl + lr * 136 + kk * 32 + lk);
#pragma unroll
      for (int j = 0; j < 4; ++j) oacc[j] = MFMA(pa, xf[kk * 4 + j], oacc[j]);
    }
    __builtin_amdgcn_s_setprio(0);
#pragma unroll
    for (int j = 0; j < 4; ++j)
#pragma unroll
      for (int e = 0; e < 4; ++e)
        Bw[(frow + e) * 72 + j * 16 + lr] = (bf16_t)oacc[j][e];
#pragma unroll
    for (int r2 = 0; r2 < 2; ++r2) {
      int row = lane >> 2, chunk = (lane & 3) + r2 * 4;
      *(bf16x8*)(tB + (size_t)row * 512 + dc * 64 + chunk * 8) =
          *(const bf16x8*)(Bw + row * 72 + chunk * 8);
    }
  }
}

// ---------------------------------------------------------------- GEMM 128x128
template <int OUTMODE, int RELU>
__global__ __launch_bounds__(256) void k_gemm(const bf16_t* __restrict__ A,
                                              const bf16_t* __restrict__ Bt,
                                              const float* __restrict__ bias,
                                              bf16_t* __restrict__ C,
                                              int M, int N, int K) {
  __shared__ __align__(16) bf16_t As[128 * 64];
  __shared__ __align__(16) bf16_t Bs[128 * 64];
  const int tid = threadIdx.x, lane = tid & 63, wave = tid >> 6;
  const int wr = (wave >> 1) * 64, wc = (wave & 1) * 64;
  const int m0 = blockIdx.x * 128, n0 = blockIdx.y * 128;
  const int lr = lane & 15, lk = (lane >> 4) * 8, frow = (lane >> 4) * 4;
  const int grow = lane >> 3;
  const int gcol = ((lane & 7) ^ grow) * 8;
  const int rmask = (lr & 7) << 3;
  f32x4 acc[4][4] = {};

  for (int kt = 0; kt < K; kt += 64) {
#pragma unroll
    for (int i = 0; i < 4; ++i) {
      int t = wave * 4 + i;
      int row = t * 8 + grow;
      gload16(A + (size_t)(m0 + row) * K + kt + gcol, As + t * 512);
      gload16(Bt + (size_t)(n0 + row) * K + kt + gcol, Bs + t * 512);
    }
    __syncthreads();
#pragma unroll
    for (int kk = 0; kk < 2; ++kk) {
      const int col = (kk * 32 + lk) ^ rmask;
      bf16x8 af[4], bfr[4];
#pragma unroll
      for (int i = 0; i < 4; ++i)
        af[i] = *(const bf16x8*)(As + (wr + i * 16 + lr) * 64 + col);
#pragma unroll
      for (int j = 0; j < 4; ++j)
        bfr[j] = *(const bf16x8*)(Bs + (wc + j * 16 + lr) * 64 + col);
#pragma unroll
      for (int i = 0; i < 4; ++i)
#pragma unroll
        for (int j = 0; j < 4; ++j)
          acc[i][j] = MFMA(af[i], bfr[j], acc[i][j]);
    }
    __syncthreads();
  }
#pragma unroll
  for (int j = 0; j < 4; ++j) {
    int gn = n0 + wc + j * 16 + lr;
    float bv = bias ? bias[gn] : 0.0f;
#pragma unroll
    for (int i = 0; i < 4; ++i) {
#pragma unroll
      for (int q = 0; q < 4; ++q) {
        int gm = m0 + wr + i * 16 + frow + q;
        float v = acc[i][j][q] + bv;
        if (RELU) v = v > 0.0f ? v : 0.0f;
        if (OUTMODE == 0)
          C[(size_t)gm * N + gn] = (bf16_t)v;
        else
          C[((size_t)(gn >> 9) * 8192 + gm) * 512 + (gn & 511)] = (bf16_t)v;
      }
    }
  }
}

// ---------------------------------------------------------------- GEMM 64x128, B from f32 W[k][n]
// C[M][N] = A[M][K] @ W[K][N slice] + bias (opt relu); B staged transposed+converted.
template <int RELU>
__global__ __launch_bounds__(256) void k_gemm64f(const bf16_t* __restrict__ A,
                                                 const float* __restrict__ Wf,
                                                 const float* __restrict__ bias,
                                                 bf16_t* __restrict__ C,
                                                 int M, int N, int K) {
  __shared__ __align__(16) bf16_t As[64 * 68];
  __shared__ __align__(16) bf16_t Bs[128 * 68];
  const int tid = threadIdx.x, lane = tid & 63, wave = tid >> 6;
  const int m0 = blockIdx.x * 64, n0 = blockIdx.y * 128;
  const int lr = lane & 15, lk = (lane >> 4) * 8, frow = (lane >> 4) * 4;
  const int sr = tid >> 3, sc = (tid & 7) * 8;
  f32x4 acc[8] = {};

  for (int kt = 0; kt < K; kt += 64) {
#pragma unroll
    for (int i = 0; i < 2; ++i) {
      int r = i * 32 + sr;
      *(bf16x8*)(As + r * 68 + sc) = *(const bf16x8*)(A + (size_t)(m0 + r) * K + kt + sc);
    }
#pragma unroll
    for (int rr = 0; rr < 8; ++rr) {
      int kr = (tid >> 5) + 8 * rr;
      int nc = (tid & 31) * 4;
      const float* bp = Wf + (size_t)(kt + kr) * N + n0 + nc;
      float4 v = *(const float4*)bp;
      Bs[(nc + 0) * 68 + kr] = (bf16_t)v.x;
      Bs[(nc + 1) * 68 + kr] = (bf16_t)v.y;
      Bs[(nc + 2) * 68 + kr] = (bf16_t)v.z;
      Bs[(nc + 3) * 68 + kr] = (bf16_t)v.w;
    }
    __syncthreads();
#pragma unroll
    for (int kk = 0; kk < 2; ++kk) {
      bf16x8 af = *(const bf16x8*)(As + (wave * 16 + lr) * 68 + kk * 32 + lk);
      bf16x8 bfr[8];
#pragma unroll
      for (int j = 0; j < 8; ++j)
        bfr[j] = *(const bf16x8*)(Bs + (j * 16 + lr) * 68 + kk * 32 + lk);
#pragma unroll
      for (int j = 0; j < 8; ++j) acc[j] = MFMA(af, bfr[j], acc[j]);
    }
    __syncthreads();
  }
#pragma unroll
  for (int j = 0; j < 8; ++j) {
    int gn = n0 + j * 16 + lr;
    float bv = bias ? bias[gn] : 0.0f;
#pragma unroll
    for (int q = 0; q < 4; ++q) {
      int gm = m0 + wave * 16 + frow + q;
      float v = acc[j][q] + bv;
      if (RELU) v = v > 0.0f ? v : 0.0f;
      C[(size_t)gm * N + gn] = (bf16_t)v;
    }
  }
}

// ---------------------------------------------------------------- inter-mixing fused GEMMs
// k_gemmT1: t1[(b,d)][s2] = relu( sum_s1 o1[b][s1][d]*Wi1[s1][s2] + bi1[s2] )
// A transposed during staging; B staged from f32 Wi1[s1][s2].
__global__ __launch_bounds__(256) void k_gemmT1(const bf16_t* __restrict__ o1,
                                                const float* __restrict__ Wi1,
                                                const float* __restrict__ bi1,
                                                bf16_t* __restrict__ t1) {
  __shared__ __align__(16) bf16_t As[64 * 68];
  __shared__ __align__(16) bf16_t Bs[128 * 68];
  const int tid = threadIdx.x, lane = tid & 63, wave = tid >> 6;
  const int m0 = blockIdx.x * 64;
  const int bb = m0 >> 9, d0 = m0 & 511;
  const int lr = lane & 15, lk = (lane >> 4) * 8, frow = (lane >> 4) * 4;
  const int sc = (tid & 7) * 8;
  f32x4 acc[8] = {};

  for (int kt = 0; kt < 128; kt += 64) {
#pragma unroll
    for (int rr = 0; rr < 2; ++rr) {
      int s = rr * 32 + (tid >> 3);
      bf16x8 v = *(const bf16x8*)(o1 + ((size_t)(bb * 128 + kt + s)) * 512 + d0 + sc);
#pragma unroll
      for (int e = 0; e < 8; ++e) As[(sc + e) * 68 + s] = v[e];
    }
#pragma unroll
    for (int rr = 0; rr < 8; ++rr) {
      int kr = (tid >> 5) + 8 * rr;
      int nc = (tid & 31) * 4;
      const float* bp = Wi1 + (size_t)(kt + kr) * 128 + nc;
      float4 v = *(const float4*)bp;
      Bs[(nc + 0) * 68 + kr] = (bf16_t)v.x;
      Bs[(nc + 1) * 68 + kr] = (bf16_t)v.y;
      Bs[(nc + 2) * 68 + kr] = (bf16_t)v.z;
      Bs[(nc + 3) * 68 + kr] = (bf16_t)v.w;
    }
    __syncthreads();
#pragma unroll
    for (int kk = 0; kk < 2; ++kk) {
      bf16x8 af = *(const bf16x8*)(As + (wave * 16 + lr) * 68 + kk * 32 + lk);
      bf16x8 bfr[8];
#pragma unroll
      for (int j = 0; j < 8; ++j)
        bfr[j] = *(const bf16x8*)(Bs + (j * 16 + lr) * 68 + kk * 32 + lk);
#pragma unroll
      for (int j = 0; j < 8; ++j) acc[j] = MFMA(af, bfr[j], acc[j]);
    }
    __syncthreads();
  }
#pragma unroll
  for (int j = 0; j < 8; ++j) {
    int gn = j * 16 + lr;
    float bv = bi1[gn];
#pragma unroll
    for (int q = 0; q < 4; ++q) {
      int gm = m0 + wave * 16 + frow + q;
      float v = acc[j][q] + bv;
      v = v > 0.0f ? v : 0.0f;
      t1[(size_t)gm * 128 + gn] = (bf16_t)v;
    }
  }
}

// k_gemmT2: y[(b,d)][s3] = sum_s2 t1[(b,d)][s2]*Wi2[s2][s3] + bi2[s3];
// stores TRANSPOSED: o1[b][s3][d]. B staged from f32 Wi2[s2][s3].
__global__ __launch_bounds__(256) void k_gemmT2(const bf16_t* __restrict__ t1,
                                                const float* __restrict__ Wi2,
                                                const float* __restrict__ bi2,
                                                bf16_t* __restrict__ o1) {
  __shared__ __align__(16) bf16_t As[64 * 68];
  __shared__ __align__(16) bf16_t Bs[128 * 68];
  __shared__ __align__(16) bf16_t Full[128 * 72];  // [n=s3][m=d']
  const int tid = threadIdx.x, lane = tid & 63, wave = tid >> 6;
  const int m0 = blockIdx.x * 64;
  const int bb = m0 >> 9, d0 = m0 & 511;
  const int lr = lane & 15, lk = (lane >> 4) * 8, frow = (lane >> 4) * 4;
  const int sr = tid >> 3, sc = (tid & 7) * 8;
  f32x4 acc[8] = {};

  for (int kt = 0; kt < 128; kt += 64) {
#pragma unroll
    for (int i = 0; i < 2; ++i) {
      int r = i * 32 + sr;
      *(bf16x8*)(As + r * 68 + sc) = *(const bf16x8*)(t1 + (size_t)(m0 + r) * 128 + kt + sc);
    }
#pragma unroll
    for (int rr = 0; rr < 8; ++rr) {
      int kr = (tid >> 5) + 8 * rr;
      int nc = (tid & 31) * 4;
      const float* bp = Wi2 + (size_t)(kt + kr) * 128 + nc;
      float4 v = *(const float4*)bp;
      Bs[(nc + 0) * 68 + kr] = (bf16_t)v.x;
      Bs[(nc + 1) * 68 + kr] = (bf16_t)v.y;
      Bs[(nc + 2) * 68 + kr] = (bf16_t)v.z;
      Bs[(nc + 3) * 68 + kr] = (bf16_t)v.w;
    }
    __syncthreads();
#pragma unroll
    for (int kk = 0; kk < 2; ++kk) {
      bf16x8 af = *(const bf16x8*)(As + (wave * 16 + lr) * 68 + kk * 32 + lk);
      bf16x8 bfr[8];
#pragma unroll
      for (int j = 0; j < 8; ++j)
        bfr[j] = *(const bf16x8*)(Bs + (j * 16 + lr) * 68 + kk * 32 + lk);
#pragma unroll
      for (int j = 0; j < 8; ++j) acc[j] = MFMA(af, bfr[j], acc[j]);
    }
    __syncthreads();
  }
#pragma unroll
  for (int j = 0; j < 8; ++j) {
    int gn = j * 16 + lr;
    float bv = bi2[gn];
#pragma unroll
    for (int q = 0; q < 4; ++q)
      Full[gn * 72 + wave * 16 + frow + q] = (bf16_t)(acc[j][q] + bv);
  }
  __syncthreads();
#pragma unroll
  for (int it = 0; it < 4; ++it) {
    int n = it * 32 + (tid >> 3);
    int mcol = (tid & 7) * 8;
    *(bf16x8*)(o1 + ((size_t)(bb * 128 + n)) * 512 + d0 + mcol) =
        *(const bf16x8*)(Full + n * 72 + mcol);
  }
}

// ---------------------------------------------------------------- GEMM2 (128x64)
template <int MODE>
__global__ __launch_bounds__(256) void k_gemm2n(const bf16_t* __restrict__ U,
                                                const bf16_t* __restrict__ bt2,
                                                float* __restrict__ o1acc,
                                                const float* __restrict__ cvec,
                                                bf16_t* __restrict__ o1b, int g) {
  __shared__ __align__(16) bf16_t As[128 * 64];
  __shared__ __align__(16) bf16_t Bs[64 * 64];
  const int tid = threadIdx.x, lane = tid & 63, wave = tid >> 6;
  const int wr = (wave >> 1) * 64, wc = (wave & 1) * 32;
  const int m0 = blockIdx.x * 128, n0 = blockIdx.y * 64;
  const int lr = lane & 15, lk = (lane >> 4) * 8, frow = (lane >> 4) * 4;
  const int grow = lane >> 3;
  const int gcol = ((lane & 7) ^ grow) * 8;
  const int rmask = (lr & 7) << 3;
  f32x4 acc[4][2] = {};

  for (int kt = 0; kt < 2048; kt += 64) {
    const int slab = kt >> 9, off = kt & 511;
#pragma unroll
    for (int i = 0; i < 4; ++i) {
      int t = wave * 4 + i;
      int row = t * 8 + grow;
      gload16(U + ((size_t)slab * 8192 + m0 + row) * 512 + off + gcol, As + t * 512);
    }
#pragma unroll
    for (int i = 0; i < 2; ++i) {
      int t = wave * 2 + i;
      int row = t * 8 + grow;
      gload16(bt2 + ((size_t)(g * 4 + slab) * 512 + n0 + row) * 512 + off + gcol,
              Bs + t * 512);
    }
    __syncthreads();
#pragma unroll
    for (int kk = 0; kk < 2; ++kk) {
      const int col = (kk * 32 + lk) ^ rmask;
      bf16x8 af[4], bfr[2];
#pragma unroll
      for (int i = 0; i < 4; ++i)
        af[i] = *(const bf16x8*)(As + (wr + i * 16 + lr) * 64 + col);
#pragma unroll
      for (int j = 0; j < 2; ++j)
        bfr[j] = *(const bf16x8*)(Bs + (wc + j * 16 + lr) * 64 + col);
#pragma unroll
      for (int i = 0; i < 4; ++i)
#pragma unroll
        for (int j = 0; j < 2; ++j)
          acc[i][j] = MFMA(af[i], bfr[j], acc[i][j]);
    }
    __syncthreads();
  }
#pragma unroll
  for (int j = 0; j < 2; ++j) {
    int gn = n0 + wc + j * 16 + lr;
#pragma unroll
    for (int i = 0; i < 4; ++i) {
#pragma unroll
      for (int q = 0; q < 4; ++q) {
        int gm = m0 + wr + i * 16 + frow + q;
        size_t idx = (size_t)gm * 512 + gn;
        if (MODE == 0)
          o1acc[idx] = acc[i][j][q];
        else
          o1b[idx] = (bf16_t)(acc[i][j][q] + o1acc[idx] + cvec[gn]);
      }
    }
  }
}

// ---------------------------------------------------------------- head (split-K 256, Wh f32 direct)
__global__ __launch_bounds__(256) void k_head_partial2(const bf16_t* __restrict__ Z,
                                                       const float* __restrict__ Wh,
                                                       float* __restrict__ part) {
  __shared__ __align__(16) bf16_t As[64 * 68];
  __shared__ __align__(16) bf16_t Bs[96 * 68];
  const int tid = threadIdx.x, lane = tid & 63, wave = tid >> 6;
  const int wr = (wave >> 1) * 32, wc = (wave & 1) * 48;
  const int lr = lane & 15, lk = (lane >> 4) * 8, frow = (lane >> 4) * 4;
  const int k0 = blockIdx.x * 256;
  const int sr = tid >> 3, sc = (tid & 7) * 8;
  f32x4 acc[2][3] = {};
  for (int kt = 0; kt < 256; kt += 64) {
#pragma unroll
    for (int i = 0; i < 2; ++i) {
      int r = i * 32 + sr;
      *(bf16x8*)(As + r * 68 + sc) = *(const bf16x8*)(Z + (size_t)r * 65536 + k0 + kt + sc);
    }
    // B staged from Wh[k][96] f32: Bs[n][k_local]
    {
      const int kr = tid >> 2;            // 0..63
      const int q4 = tid & 3;             // quarter of the 96-wide row
      const float* bp = Wh + (size_t)(k0 + kt + kr) * 96 + q4 * 24;
#pragma unroll
      for (int e = 0; e < 6; ++e) {
        float4 v = *(const float4*)(bp + e * 4);
        int n = q4 * 24 + e * 4;
        Bs[(n + 0) * 68 + kr] = (bf16_t)v.x;
        Bs[(n + 1) * 68 + kr] = (bf16_t)v.y;
        Bs[(n + 2) * 68 + kr] = (bf16_t)v.z;
        Bs[(n + 3) * 68 + kr] = (bf16_t)v.w;
      }
    }
    __syncthreads();
#pragma unroll
    for (int kk = 0; kk < 2; ++kk) {
      bf16x8 af[2], bfr[3];
#pragma unroll
      for (int i = 0; i < 2; ++i)
        af[i] = *(const bf16x8*)(As + (wr + i * 16 + lr) * 68 + kk * 32 + lk);
#pragma unroll
      for (int j = 0; j < 3; ++j)
        bfr[j] = *(const bf16x8*)(Bs + (wc + j * 16 + lr) * 68 + kk * 32 + lk);
#pragma unroll
      for (int i = 0; i < 2; ++i)
#pragma unroll
        for (int j = 0; j < 3; ++j)
          acc[i][j] = MFMA(af[i], bfr[j], acc[i][j]);
    }
    __syncthreads();
  }
#pragma unroll
  for (int i = 0; i < 2; ++i)
#pragma unroll
    for (int j = 0; j < 3; ++j)
#pragma unroll
      for (int q = 0; q < 4; ++q) {
        int m = wr + i * 16 + frow + q;
        int n = wc + j * 16 + lr;
        part[(size_t)blockIdx.x * 6144 + m * 96 + n] = acc[i][j][q];
      }
}

__global__ __launch_bounds__(256) void k_head_reduce(const float* __restrict__ part,
                                                     const float* __restrict__ bias,
                                                     float* __restrict__ out) {
  int idx = blockIdx.x * 256 + threadIdx.x;
  if (idx >= 6144) return;
  float s = bias[idx % 96];
  for (int kb = 0; kb < 256; ++kb) s += part[(size_t)kb * 6144 + idx];
  out[idx] = s;
}

__global__ void k_sentinel(float* out, int n, float val) {
  int i = blockIdx.x * 256 + threadIdx.x;
  if (i < n) out[i] = val;
}

// ---------------------------------------------------------------- launch
extern "C" void kernel_launch(void* const* d_in, const int* in_sizes, int n_in,
                              void* d_out, int out_size, void* d_ws, size_t ws_size,
                              hipStream_t stream) {
  const float* x    = (const float*)d_in[0];
  const float* prev = (const float*)d_in[1];
  const float* Wq = (const float*)d_in[2];   const float* bq = (const float*)d_in[3];
  const float* Wk = (const float*)d_in[4];   const float* bk = (const float*)d_in[5];
  const float* Wv = (const float*)d_in[6];   const float* bv = (const float*)d_in[7];
  const float* Wo = (const float*)d_in[8];   const float* bo = (const float*)d_in[9];
  const float* scale = (const float*)d_in[10];
  const float* Wi1 = (const float*)d_in[11]; const float* bi1 = (const float*)d_in[12];
  const float* Wi2 = (const float*)d_in[13]; const float* bi2 = (const float*)d_in[14];
  const float* Wt1 = (const float*)d_in[15]; const float* bt1w = (const float*)d_in[16];
  const float* Wt2 = (const float*)d_in[17]; const float* bt2w = (const float*)d_in[18];
  const float* Wh = (const float*)d_in[19];  const float* bh = (const float*)d_in[20];
  float* out = (float*)d_out;

  char* p = (char*)d_ws;
  auto carve = [&](size_t bytes) {
    char* r = p;
    p += (bytes + 255) & ~(size_t)255;
    return r;
  };
  bf16_t* xb    = (bf16_t*)carve((size_t)8192 * 512 * 2);
  bf16_t* xTo1b = (bf16_t*)carve((size_t)8192 * 512 * 2);
  float*  o1acc = (float*)carve((size_t)8192 * 512 * 4);
  bf16_t* bt1   = (bf16_t*)carve((size_t)4096 * 512 * 2);
  bf16_t* bt2   = (bf16_t*)carve((size_t)4096 * 512 * 2);
  bf16_t* W12b  = (bf16_t*)carve(16 * 512 * 2);
  float*  cb    = (float*)carve(8 * 4);
  float*  cvec  = (float*)carve(512 * 4);
  char*   arena = carve((size_t)8192 * 2048 * 2);
  bf16_t* TU    = (bf16_t*)arena;
  float*  cpart = (float*)arena;
  bf16_t* xT    = xTo1b;
  bf16_t* o1b   = xTo1b;
  float*  TallT = (float*)bt1;
  char* q2 = arena;
  auto carve2 = [&](size_t bytes) {
    char* r = q2;
    q2 += (bytes + 255) & ~(size_t)255;
    return r;
  };
  float*  hp   = (float*)carve2((size_t)256 * 64 * 96 * 4);
  bf16_t* bufB = (bf16_t*)carve2((size_t)8192 * 512 * 2);

  if ((size_t)(p - (char*)d_ws) > ws_size) {
    k_sentinel<<<24, 256, 0, stream>>>(out, 6144, (float)ws_size);
    return;
  }

  dim3 blk(256);
  // ---- prep
  k_cvec1<<<32, blk, 0, stream>>>(bv, Wo, cpart);
  k_cvec2<<<2, blk, 0, stream>>>(cpart, bo, cvec);
  k_convert_dual<<<dim3(16, 256), blk, 0, stream>>>(x, xb, xT);
  k_wprod<0><<<dim3(4, 4, 8), blk, 0, stream>>>(Wq, Wk, bt1, 4096, 4096);
  k_wprod<1><<<dim3(4, 4, 8), blk, 0, stream>>>(Wv, Wo, bt2, 4096, 512);
  k_sbias2<<<128, blk, 0, stream>>>(Wq, bk, Wk, bq, W12b, cb);

  // ---- attention path, 2 head-groups (attn9 both — best measured variant)
  // g=0
  k_gemm<2, 0><<<dim3(64, 16), blk, 0, stream>>>(xb, bt1, nullptr, TU, 8192, 2048, 512);
  k_tbias2<<<128, blk, 0, stream>>>(xb, W12b, cb, TallT);
  k_attn9<<<2048, dim3(64), 0, stream>>>(xb, xT, TU, prev, scale, TallT, 0);
  k_gemm2n<0><<<dim3(64, 8), blk, 0, stream>>>(TU, bt2, o1acc, cvec, o1b, 0);
  // g=1
  k_gemm<2, 0><<<dim3(64, 16), blk, 0, stream>>>(xb, bt1 + (size_t)2048 * 512, nullptr, TU,
                                                 8192, 2048, 512);
  k_attn9<<<2048, dim3(64), 0, stream>>>(xb, xT, TU, prev, scale, TallT, 1);
  k_gemm2n<1><<<dim3(64, 8), blk, 0, stream>>>(TU, bt2, o1acc, cvec, o1b, 1);

  // ---- InterPatchMixing: fused transposed GEMMs, weights read f32-direct
  k_gemmT1<<<512, blk, 0, stream>>>(o1b, Wi1, bi1, bufB);
  k_gemmT2<<<512, blk, 0, stream>>>(bufB, Wi2, bi2, o1b);

  // ---- IntraPatchMixing: weights read f32-direct (transposed staging)
  k_gemm64f<1><<<dim3(128, 4), blk, 0, stream>>>(o1b, Wt1, bt1w, bufB, 8192, 512, 512);
  k_gemm64f<0><<<dim3(128, 4), blk, 0, stream>>>(bufB, Wt2, bt2w, o1b, 8192, 512, 512);

  // ---- Flatten head: split-K=256, Wh f32 direct
  k_head_partial2<<<256, blk, 0, stream>>>(o1b, Wh, hp);
  k_head_reduce<<<24, blk, 0, stream>>>(hp, bh, out);
}

// Round 19
// 443.554 us; speedup vs baseline: 1.0414x; 1.0414x over previous
//
#include <hip/hip_runtime.h>
#include <cstdint>
#include <cstddef>

typedef __bf16 bf16_t;
typedef __bf16 bf16x8 __attribute__((ext_vector_type(8)));
typedef __bf16 bf16x4 __attribute__((ext_vector_type(4)));
typedef float  f32x4  __attribute__((ext_vector_type(4)));

#define MFMA(a, b, c) __builtin_amdgcn_mfma_f32_16x16x32_bf16((a), (b), (c), 0, 0, 0)

// async global->LDS, 16B/lane; dest = wave-uniform base + lane*16 (linear)
__device__ __forceinline__ void gload16(const bf16_t* g, bf16_t* l) {
  __builtin_amdgcn_global_load_lds(
      (const __attribute__((address_space(1))) void*)g,
      (__attribute__((address_space(3))) void*)l, 16, 0, 0);
}

// BS=64, S=128, DM=512, H=8, PRED=96, NF=65536

// ---------------------------------------------------------------- converts
__global__ __launch_bounds__(256) void k_convert_dual(const float* __restrict__ in,
                                                      bf16_t* __restrict__ xb,
                                                      bf16_t* __restrict__ xT) {
  __shared__ bf16_t tile[32][34];
  int tx = threadIdx.x & 31, ty = threadIdx.x >> 5;
  int c0 = blockIdx.x * 32, r0 = blockIdx.y * 32;
#pragma unroll
  for (int j = 0; j < 4; ++j) {
    int r = r0 + ty + j * 8;
    bf16_t bv = (bf16_t)in[(size_t)r * 512 + c0 + tx];
    xb[(size_t)r * 512 + c0 + tx] = bv;
    tile[ty + j * 8][tx] = bv;
  }
  __syncthreads();
  int b = (r0 + tx) >> 7, s = (r0 + tx) & 127;
#pragma unroll
  for (int j = 0; j < 4; ++j) {
    int i = c0 + ty + j * 8;
    xT[(size_t)b * 65536 + (size_t)i * 128 + s] = tile[tx][ty + j * 8];
  }
}

__global__ __launch_bounds__(256) void k_transpose_convert(const float* __restrict__ in,
                                                           bf16_t* __restrict__ out,
                                                           int R, int C) {
  __shared__ float tile[32][33];
  int tx = threadIdx.x & 31, ty = threadIdx.x >> 5;
  int c0 = blockIdx.x * 32, r0 = blockIdx.y * 32;
#pragma unroll
  for (int j = 0; j < 4; ++j)
    tile[ty + j * 8][tx] = in[(size_t)(r0 + ty + j * 8) * C + c0 + tx];
  __syncthreads();
#pragma unroll
  for (int j = 0; j < 4; ++j)
    out[(size_t)(c0 + ty + j * 8) * R + r0 + tx] = (bf16_t)tile[tx][ty + j * 8];
}

// ---------------------------------------------------------------- weight products
template <int BMODE>
__global__ __launch_bounds__(256) void k_wprod(const float* __restrict__ Ap,
                                               const float* __restrict__ Bp,
                                               bf16_t* __restrict__ out,
                                               int ldA, int ldB) {
  __shared__ __align__(16) bf16_t S[128 * 68 * 2];
  bf16_t* As = S;
  bf16_t* Bs = S + 128 * 68;
  const int tid = threadIdx.x, lane = tid & 63, wave = tid >> 6;
  const int wr = (wave >> 1) * 64, wc = (wave & 1) * 64;
  const int lr = lane & 15, lk = (lane >> 4) * 8, frow = (lane >> 4) * 4;
  const int m0 = blockIdx.x * 128, n0 = blockIdx.y * 128, h = blockIdx.z;
  const int sr = tid >> 3, sc = (tid & 7) * 8;
  f32x4 acc[4][4] = {};

  for (int kt = 0; kt < 512; kt += 64) {
#pragma unroll
    for (int rr = 0; rr < 4; ++rr) {
      int r = sr + 32 * rr;
      const float* ap = Ap + (size_t)(m0 + r) * ldA + h * 512 + kt + sc;
      bf16x8 av;
#pragma unroll
      for (int e = 0; e < 8; ++e) av[e] = (bf16_t)ap[e];
      *(bf16x8*)(As + r * 68 + sc) = av;
    }
    if (BMODE == 0) {
#pragma unroll
      for (int rr = 0; rr < 4; ++rr) {
        int r = sr + 32 * rr;
        const float* bp = Bp + (size_t)(n0 + r) * ldB + h * 512 + kt + sc;
        bf16x8 bv;
#pragma unroll
        for (int e = 0; e < 8; ++e) bv[e] = (bf16_t)bp[e];
        *(bf16x8*)(Bs + r * 68 + sc) = bv;
      }
    } else {
#pragma unroll
      for (int rr = 0; rr < 8; ++rr) {
        int kr = (tid >> 5) + 8 * rr;
        int nc = (tid & 31) * 4;
        const float* bp = Bp + (size_t)(h * 512 + kt + kr) * ldB + n0 + nc;
        float4 v = *(const float4*)bp;
        Bs[(nc + 0) * 68 + kr] = (bf16_t)v.x;
        Bs[(nc + 1) * 68 + kr] = (bf16_t)v.y;
        Bs[(nc + 2) * 68 + kr] = (bf16_t)v.z;
        Bs[(nc + 3) * 68 + kr] = (bf16_t)v.w;
      }
    }
    __syncthreads();
#pragma unroll
    for (int kk = 0; kk < 2; ++kk) {
      bf16x8 af[4], bfr[4];
#pragma unroll
      for (int i = 0; i < 4; ++i)
        af[i] = *(const bf16x8*)(As + (wr + i * 16 + lr) * 68 + kk * 32 + lk);
#pragma unroll
      for (int j = 0; j < 4; ++j)
        bfr[j] = *(const bf16x8*)(Bs + (wc + j * 16 + lr) * 68 + kk * 32 + lk);
#pragma unroll
      for (int i = 0; i < 4; ++i)
#pragma unroll
        for (int j = 0; j < 4; ++j)
          acc[i][j] = MFMA(af[i], bfr[j], acc[i][j]);
    }
    __syncthreads();
  }

  bf16_t* Full = S;  // [128 n][136 m]
#pragma unroll
  for (int i = 0; i < 4; ++i)
#pragma unroll
    for (int j = 0; j < 4; ++j)
#pragma unroll
      for (int q = 0; q < 4; ++q)
        Full[(wc + j * 16 + lr) * 136 + wr + i * 16 + frow + q] = (bf16_t)acc[i][j][q];
  __syncthreads();
#pragma unroll
  for (int it = 0; it < 8; ++it) {
    int r = it * 16 + (tid >> 4);
    int c = (tid & 15) * 8;
    *(bf16x8*)(out + ((size_t)(h * 512 + n0 + r)) * 512 + m0 + c) =
        *(const bf16x8*)(Full + r * 136 + c);
  }
}

// ---------------------------------------------------------------- bias helpers
__global__ __launch_bounds__(256) void k_sbias2(const float* __restrict__ Wq,
                                                const float* __restrict__ bk,
                                                const float* __restrict__ Wk,
                                                const float* __restrict__ bq,
                                                bf16_t* __restrict__ W12b,
                                                float* __restrict__ c) {
  const int lane = threadIdx.x & 63, wave = threadIdx.x >> 6;
  const int i = blockIdx.x * 4 + wave;
  for (int h = 0; h < 8; ++h) {
    float s1 = 0.f, s2 = 0.f;
    for (int d = lane; d < 512; d += 64) {
      s1 += Wq[(size_t)i * 4096 + h * 512 + d] * bk[h * 512 + d];
      s2 += Wk[(size_t)i * 4096 + h * 512 + d] * bq[h * 512 + d];
    }
#pragma unroll
    for (int o = 32; o > 0; o >>= 1) { s1 += __shfl_down(s1, o); s2 += __shfl_down(s2, o); }
    if (lane == 0) {
      W12b[h * 512 + i] = (bf16_t)s1;
      W12b[(8 + h) * 512 + i] = (bf16_t)s2;
    }
  }
  if (blockIdx.x == 0 && wave == 0) {
    for (int h = 0; h < 8; ++h) {
      float cc = 0.f;
      for (int d = lane; d < 512; d += 64) cc += bq[h * 512 + d] * bk[h * 512 + d];
#pragma unroll
      for (int o = 32; o > 0; o >>= 1) cc += __shfl_down(cc, o);
      if (lane == 0) c[h] = cc;
    }
  }
}

// TallT[16][8192] f32 = x @ W12^T (+cb for c<8), MFMA
__global__ __launch_bounds__(256) void k_tbias2(const bf16_t* __restrict__ xb,
                                                const bf16_t* __restrict__ W12b,
                                                const float* __restrict__ cb,
                                                float* __restrict__ TallT) {
  __shared__ __align__(16) bf16_t Ws[16 * 516];
  const int tid = threadIdx.x, lane = tid & 63, wave = tid >> 6;
  const int lr = lane & 15, lk = (lane >> 4) * 8, frow = (lane >> 4) * 4;
  for (int i = tid; i < 1024; i += 256) {
    int r = i >> 6, ccol = (i & 63) * 8;
    *(bf16x8*)(Ws + r * 516 + ccol) = *(const bf16x8*)(W12b + r * 512 + ccol);
  }
  __syncthreads();
  const int row0 = blockIdx.x * 64 + wave * 16;
  const bf16_t* xr = xb + (size_t)(row0 + lr) * 512 + lk;
  f32x4 acc = {};
#pragma unroll
  for (int kx = 0; kx < 16; ++kx) {
    bf16x8 af = *(const bf16x8*)(xr + kx * 32);
    bf16x8 bfv = *(const bf16x8*)(Ws + lr * 516 + kx * 32 + lk);
    acc = MFMA(af, bfv, acc);
  }
#pragma unroll
  for (int q = 0; q < 4; ++q) {
    int r = row0 + frow + q;
    float v = acc[q] + (lr < 8 ? cb[lr] : 0.f);
    TallT[(size_t)lr * 8192 + r] = v;
  }
}

// cvec = bv @ Wo + bo, 2-stage
__global__ __launch_bounds__(256) void k_cvec1(const float* __restrict__ bv,
                                               const float* __restrict__ Wo,
                                               float* __restrict__ cpart) {
  int cch = blockIdx.x, d = threadIdx.x * 2;
  float ax = 0.f, ay = 0.f;
  for (int n = cch * 128; n < cch * 128 + 128; ++n) {
    float b = bv[n];
    float2 w = *(const float2*)(Wo + (size_t)n * 512 + d);
    ax += b * w.x; ay += b * w.y;
  }
  cpart[(size_t)cch * 512 + d] = ax;
  cpart[(size_t)cch * 512 + d + 1] = ay;
}
__global__ __launch_bounds__(256) void k_cvec2(const float* __restrict__ cpart,
                                               const float* __restrict__ bo,
                                               float* __restrict__ cvec) {
  int d = blockIdx.x * 256 + threadIdx.x;
  float s = bo[d];
  for (int cch = 0; cch < 32; ++cch) s += cpart[(size_t)cch * 512 + d];
  cvec[d] = s;
}

// ---------------------------------------------------------------- attention core
// k_attn9 (best measured: 73 us). 1-wave blocks, grid 2048, batched direct loads.
__global__ __launch_bounds__(64, 2) void k_attn9(const bf16_t* __restrict__ xb,
                                                 const bf16_t* __restrict__ xT,
                                                 bf16_t* __restrict__ TU,
                                                 const float* __restrict__ prev,
                                                 const float* __restrict__ scale_p,
                                                 const float* __restrict__ TallT,
                                                 int hg) {
  __shared__ __align__(16) bf16_t Pl[16 * 136];
  __shared__ __align__(16) bf16_t Bw[16 * 72];

  const int lane = threadIdx.x;
  const int lr = lane & 15, lk = (lane >> 4) * 8, frow = (lane >> 4) * 4;
  const int bid = blockIdx.x;
  const int bx = (bid & 7) * 256 + (bid >> 3);
  const int b = bx >> 5, hp = (bx >> 3) & 3, rg = bx & 7;
  const int h = hg * 4 + hp;
  const int r0 = rg * 16;
  const bf16_t* xB = xb + (size_t)b * 65536;
  const bf16_t* xTB = xT + (size_t)b * 65536;
  bf16_t* tB = TU + ((size_t)hp * 8192 + b * 128 + r0) * 512;

  bf16x8 tf[16];
  const bf16_t* aP = tB + (size_t)lr * 512 + lk;
#pragma unroll
  for (int kx = 0; kx < 16; ++kx) tf[kx] = *(const bf16x8*)(aP + kx * 32);

  f32x4 sacc[8] = {};
  const bf16_t* bP = xB + (size_t)lr * 512 + lk;
#pragma unroll
  for (int kc = 0; kc < 8; ++kc) {
    bf16x8 bb0[8], bb1[8];
#pragma unroll
    for (int j = 0; j < 8; ++j)
      bb0[j] = *(const bf16x8*)(bP + (size_t)j * 8192 + (2 * kc) * 32);
#pragma unroll
    for (int j = 0; j < 8; ++j)
      bb1[j] = *(const bf16x8*)(bP + (size_t)j * 8192 + (2 * kc + 1) * 32);
    __builtin_amdgcn_s_setprio(1);
#pragma unroll
    for (int j = 0; j < 8; ++j) sacc[j] = MFMA(tf[2 * kc], bb0[j], sacc[j]);
#pragma unroll
    for (int j = 0; j < 8; ++j) sacc[j] = MFMA(tf[2 * kc + 1], bb1[j], sacc[j]);
    __builtin_amdgcn_s_setprio(0);
  }

  const float scl = scale_p[0];
  const float* t1p = TallT + h * 8192 + b * 128 + r0;
  const float* t2p = TallT + (8 + h) * 8192 + b * 128;
  float t2r[8];
#pragma unroll
  for (int j = 0; j < 8; ++j) t2r[j] = t2p[j * 16 + lr];
#pragma unroll
  for (int e = 0; e < 4; ++e) {
    const int rl = frow + e;
    const float t1 = t1p[rl];
    const float* prow = prev + (((size_t)(b * 8 + h)) * 128 + r0 + rl) * 128;
    float pv[8];
#pragma unroll
    for (int j = 0; j < 8; ++j) pv[j] = prow[j * 16 + lr];
    float mx = -3.4e38f;
#pragma unroll
    for (int j = 0; j < 8; ++j) {
      float v = scl * (sacc[j][e] + t1 + t2r[j]) + pv[j];
      sacc[j][e] = v;
      mx = fmaxf(mx, v);
    }
    mx = fmaxf(mx, __shfl_xor(mx, 1));
    mx = fmaxf(mx, __shfl_xor(mx, 2));
    mx = fmaxf(mx, __shfl_xor(mx, 4));
    mx = fmaxf(mx, __shfl_xor(mx, 8));
    float sum = 0.f;
#pragma unroll
    for (int j = 0; j < 8; ++j) {
      float p = __expf(sacc[j][e] - mx);
      sacc[j][e] = p;
      sum += p;
    }
    sum += __shfl_xor(sum, 1);
    sum += __shfl_xor(sum, 2);
    sum += __shfl_xor(sum, 4);
    sum += __shfl_xor(sum, 8);
    float inv = 1.f / sum;
#pragma unroll
    for (int j = 0; j < 8; ++j)
      Pl[rl * 136 + j * 16 + lr] = (bf16_t)(sacc[j][e] * inv);
  }

#pragma unroll
  for (int dc = 0; dc < 8; ++dc) {
    bf16x8 xf[16];
#pragma unroll
    for (int kk = 0; kk < 4; ++kk)
#pragma unroll
      for (int j = 0; j < 4; ++j)
        xf[kk * 4 + j] =
            *(const bf16x8*)(xTB + (size_t)(dc * 64 + j * 16 + lr) * 128 + kk * 32 + lk);
    f32x4 oacc[4] = {};
    __builtin_amdgcn_s_setprio(1);
#pragma unroll
    for (int kk = 0; kk < 4; ++kk) {
      bf16x8 pa = *(const bf16x8*)(Pl + lr * 136 + kk * 32 + lk);
#pragma unroll
      for (int j = 0; j < 4; ++j) oacc[j] = MFMA(pa, xf[kk * 4 + j], oacc[j]);
    }
    __builtin_amdgcn_s_setprio(0);
#pragma unroll
    for (int j = 0; j < 4; ++j)
#pragma unroll
      for (int e = 0; e < 4; ++e)
        Bw[(frow + e) * 72 + j * 16 + lr] = (bf16_t)oacc[j][e];
#pragma unroll
    for (int r2 = 0; r2 < 2; ++r2) {
      int row = lane >> 2, chunk = (lane & 3) + r2 * 4;
      *(bf16x8*)(tB + (size_t)row * 512 + dc * 64 + chunk * 8) =
          *(const bf16x8*)(Bw + row * 72 + chunk * 8);
    }
  }
}

// ---------------------------------------------------------------- GEMM 128x128
template <int OUTMODE, int RELU>
__global__ __launch_bounds__(256) void k_gemm(const bf16_t* __restrict__ A,
                                              const bf16_t* __restrict__ Bt,
                                              const float* __restrict__ bias,
                                              bf16_t* __restrict__ C,
                                              int M, int N, int K) {
  __shared__ __align__(16) bf16_t As[128 * 64];
  __shared__ __align__(16) bf16_t Bs[128 * 64];
  const int tid = threadIdx.x, lane = tid & 63, wave = tid >> 6;
  const int wr = (wave >> 1) * 64, wc = (wave & 1) * 64;
  const int m0 = blockIdx.x * 128, n0 = blockIdx.y * 128;
  const int lr = lane & 15, lk = (lane >> 4) * 8, frow = (lane >> 4) * 4;
  const int grow = lane >> 3;
  const int gcol = ((lane & 7) ^ grow) * 8;
  const int rmask = (lr & 7) << 3;
  f32x4 acc[4][4] = {};

  for (int kt = 0; kt < K; kt += 64) {
#pragma unroll
    for (int i = 0; i < 4; ++i) {
      int t = wave * 4 + i;
      int row = t * 8 + grow;
      gload16(A + (size_t)(m0 + row) * K + kt + gcol, As + t * 512);
      gload16(Bt + (size_t)(n0 + row) * K + kt + gcol, Bs + t * 512);
    }
    __syncthreads();
#pragma unroll
    for (int kk = 0; kk < 2; ++kk) {
      const int col = (kk * 32 + lk) ^ rmask;
      bf16x8 af[4], bfr[4];
#pragma unroll
      for (int i = 0; i < 4; ++i)
        af[i] = *(const bf16x8*)(As + (wr + i * 16 + lr) * 64 + col);
#pragma unroll
      for (int j = 0; j < 4; ++j)
        bfr[j] = *(const bf16x8*)(Bs + (wc + j * 16 + lr) * 64 + col);
#pragma unroll
      for (int i = 0; i < 4; ++i)
#pragma unroll
        for (int j = 0; j < 4; ++j)
          acc[i][j] = MFMA(af[i], bfr[j], acc[i][j]);
    }
    __syncthreads();
  }
#pragma unroll
  for (int j = 0; j < 4; ++j) {
    int gn = n0 + wc + j * 16 + lr;
    float bv = bias ? bias[gn] : 0.0f;
#pragma unroll
    for (int i = 0; i < 4; ++i) {
#pragma unroll
      for (int q = 0; q < 4; ++q) {
        int gm = m0 + wr + i * 16 + frow + q;
        float v = acc[i][j][q] + bv;
        if (RELU) v = v > 0.0f ? v : 0.0f;
        if (OUTMODE == 0)
          C[(size_t)gm * N + gn] = (bf16_t)v;
        else
          C[((size_t)(gn >> 9) * 8192 + gm) * 512 + (gn & 511)] = (bf16_t)v;
      }
    }
  }
}

// ---------------------------------------------------------------- GEMM 64x128 (reg-staged, padded)
template <int RELU>
__global__ __launch_bounds__(256) void k_gemm64(const bf16_t* __restrict__ A,
                                                const bf16_t* __restrict__ Bt,
                                                const float* __restrict__ bias,
                                                bf16_t* __restrict__ C,
                                                int M, int N, int K) {
  __shared__ __align__(16) bf16_t As[64 * 68];
  __shared__ __align__(16) bf16_t Bs[128 * 68];
  const int tid = threadIdx.x, lane = tid & 63, wave = tid >> 6;
  const int m0 = blockIdx.x * 64, n0 = blockIdx.y * 128;
  const int lr = lane & 15, lk = (lane >> 4) * 8, frow = (lane >> 4) * 4;
  const int sr = tid >> 3, sc = (tid & 7) * 8;
  f32x4 acc[8] = {};

  for (int kt = 0; kt < K; kt += 64) {
#pragma unroll
    for (int i = 0; i < 2; ++i) {
      int r = i * 32 + sr;
      *(bf16x8*)(As + r * 68 + sc) = *(const bf16x8*)(A + (size_t)(m0 + r) * K + kt + sc);
    }
#pragma unroll
    for (int i = 0; i < 4; ++i) {
      int r = i * 32 + sr;
      *(bf16x8*)(Bs + r * 68 + sc) = *(const bf16x8*)(Bt + (size_t)(n0 + r) * K + kt + sc);
    }
    __syncthreads();
#pragma unroll
    for (int kk = 0; kk < 2; ++kk) {
      bf16x8 af = *(const bf16x8*)(As + (wave * 16 + lr) * 68 + kk * 32 + lk);
      bf16x8 bfr[8];
#pragma unroll
      for (int j = 0; j < 8; ++j)
        bfr[j] = *(const bf16x8*)(Bs + (j * 16 + lr) * 68 + kk * 32 + lk);
#pragma unroll
      for (int j = 0; j < 8; ++j) acc[j] = MFMA(af, bfr[j], acc[j]);
    }
    __syncthreads();
  }
#pragma unroll
  for (int j = 0; j < 8; ++j) {
    int gn = n0 + j * 16 + lr;
    float bv = bias ? bias[gn] : 0.0f;
#pragma unroll
    for (int q = 0; q < 4; ++q) {
      int gm = m0 + wave * 16 + frow + q;
      float v = acc[j][q] + bv;
      if (RELU) v = v > 0.0f ? v : 0.0f;
      C[(size_t)gm * N + gn] = (bf16_t)v;
    }
  }
}

// ---------------------------------------------------------------- inter-mixing fused GEMMs
// k_gemmT1: t1[(b,d)][s2] = relu( sum_s1 o1[b][s1][d]*Wi1[s1][s2] + bi1[s2] )
__global__ __launch_bounds__(256) void k_gemmT1(const bf16_t* __restrict__ o1,
                                                const bf16_t* __restrict__ wi1T,
                                                const float* __restrict__ bi1,
                                                bf16_t* __restrict__ t1) {
  __shared__ __align__(16) bf16_t As[64 * 68];
  __shared__ __align__(16) bf16_t Bs[128 * 68];
  const int tid = threadIdx.x, lane = tid & 63, wave = tid >> 6;
  const int m0 = blockIdx.x * 64;            // global d-row (b = m0>>9)
  const int bb = m0 >> 9, d0 = m0 & 511;
  const int lr = lane & 15, lk = (lane >> 4) * 8, frow = (lane >> 4) * 4;
  const int sr = tid >> 3, sc = (tid & 7) * 8;
  f32x4 acc[8] = {};

  for (int kt = 0; kt < 128; kt += 64) {
    // A staged transposed: As[m=d'][k=s] = o1[bb][kt+s][d0+d']
#pragma unroll
    for (int rr = 0; rr < 2; ++rr) {
      int s = rr * 32 + (tid >> 3);
      bf16x8 v = *(const bf16x8*)(o1 + ((size_t)(bb * 128 + kt + s)) * 512 + d0 + sc);
#pragma unroll
      for (int e = 0; e < 8; ++e) As[(sc + e) * 68 + s] = v[e];
    }
#pragma unroll
    for (int i = 0; i < 4; ++i) {
      int r = i * 32 + sr;
      *(bf16x8*)(Bs + r * 68 + sc) = *(const bf16x8*)(wi1T + (size_t)r * 128 + kt + sc);
    }
    __syncthreads();
#pragma unroll
    for (int kk = 0; kk < 2; ++kk) {
      bf16x8 af = *(const bf16x8*)(As + (wave * 16 + lr) * 68 + kk * 32 + lk);
      bf16x8 bfr[8];
#pragma unroll
      for (int j = 0; j < 8; ++j)
        bfr[j] = *(const bf16x8*)(Bs + (j * 16 + lr) * 68 + kk * 32 + lk);
#pragma unroll
      for (int j = 0; j < 8; ++j) acc[j] = MFMA(af, bfr[j], acc[j]);
    }
    __syncthreads();
  }
#pragma unroll
  for (int j = 0; j < 8; ++j) {
    int gn = j * 16 + lr;
    float bv = bi1[gn];
#pragma unroll
    for (int q = 0; q < 4; ++q) {
      int gm = m0 + wave * 16 + frow + q;
      float v = acc[j][q] + bv;
      v = v > 0.0f ? v : 0.0f;
      t1[(size_t)gm * 128 + gn] = (bf16_t)v;
    }
  }
}

// k_gemmT2: y[(b,d)][s3] = sum_s2 t1[(b,d)][s2]*Wi2[s2][s3] + bi2[s3];
// stores TRANSPOSED: o1[b][s3][d] = y.
__global__ __launch_bounds__(256) void k_gemmT2(const bf16_t* __restrict__ t1,
                                                const bf16_t* __restrict__ wi2T,
                                                const float* __restrict__ bi2,
                                                bf16_t* __restrict__ o1) {
  __shared__ __align__(16) bf16_t As[64 * 68];
  __shared__ __align__(16) bf16_t Bs[128 * 68];
  __shared__ __align__(16) bf16_t Full[128 * 72];  // [n=s3][m=d']
  const int tid = threadIdx.x, lane = tid & 63, wave = tid >> 6;
  const int m0 = blockIdx.x * 64;
  const int bb = m0 >> 9, d0 = m0 & 511;
  const int lr = lane & 15, lk = (lane >> 4) * 8, frow = (lane >> 4) * 4;
  const int sr = tid >> 3, sc = (tid & 7) * 8;
  f32x4 acc[8] = {};

  for (int kt = 0; kt < 128; kt += 64) {
#pragma unroll
    for (int i = 0; i < 2; ++i) {
      int r = i * 32 + sr;
      *(bf16x8*)(As + r * 68 + sc) = *(const bf16x8*)(t1 + (size_t)(m0 + r) * 128 + kt + sc);
    }
#pragma unroll
    for (int i = 0; i < 4; ++i) {
      int r = i * 32 + sr;
      *(bf16x8*)(Bs + r * 68 + sc) = *(const bf16x8*)(wi2T + (size_t)r * 128 + kt + sc);
    }
    __syncthreads();
#pragma unroll
    for (int kk = 0; kk < 2; ++kk) {
      bf16x8 af = *(const bf16x8*)(As + (wave * 16 + lr) * 68 + kk * 32 + lk);
      bf16x8 bfr[8];
#pragma unroll
      for (int j = 0; j < 8; ++j)
        bfr[j] = *(const bf16x8*)(Bs + (j * 16 + lr) * 68 + kk * 32 + lk);
#pragma unroll
      for (int j = 0; j < 8; ++j) acc[j] = MFMA(af, bfr[j], acc[j]);
    }
    __syncthreads();
  }
  // epilogue: bias + transpose via LDS -> coalesced store o1[b][s3][d]
#pragma unroll
  for (int j = 0; j < 8; ++j) {
    int gn = j * 16 + lr;
    float bv = bi2[gn];
#pragma unroll
    for (int q = 0; q < 4; ++q)
      Full[gn * 72 + wave * 16 + frow + q] = (bf16_t)(acc[j][q] + bv);
  }
  __syncthreads();
#pragma unroll
  for (int it = 0; it < 4; ++it) {
    int n = it * 32 + (tid >> 3);
    int mcol = (tid & 7) * 8;
    *(bf16x8*)(o1 + ((size_t)(bb * 128 + n)) * 512 + d0 + mcol) =
        *(const bf16x8*)(Full + n * 72 + mcol);
  }
}

// ---------------------------------------------------------------- GEMM2 (128x64)
template <int MODE>
__global__ __launch_bounds__(256) void k_gemm2n(const bf16_t* __restrict__ U,
                                                const bf16_t* __restrict__ bt2,
                                                float* __restrict__ o1acc,
                                                const float* __restrict__ cvec,
                                                bf16_t* __restrict__ o1b, int g) {
  __shared__ __align__(16) bf16_t As[128 * 64];
  __shared__ __align__(16) bf16_t Bs[64 * 64];
  const int tid = threadIdx.x, lane = tid & 63, wave = tid >> 6;
  const int wr = (wave >> 1) * 64, wc = (wave & 1) * 32;
  const int m0 = blockIdx.x * 128, n0 = blockIdx.y * 64;
  const int lr = lane & 15, lk = (lane >> 4) * 8, frow = (lane >> 4) * 4;
  const int grow = lane >> 3;
  const int gcol = ((lane & 7) ^ grow) * 8;
  const int rmask = (lr & 7) << 3;
  f32x4 acc[4][2] = {};

  for (int kt = 0; kt < 2048; kt += 64) {
    const int slab = kt >> 9, off = kt & 511;
#pragma unroll
    for (int i = 0; i < 4; ++i) {
      int t = wave * 4 + i;
      int row = t * 8 + grow;
      gload16(U + ((size_t)slab * 8192 + m0 + row) * 512 + off + gcol, As + t * 512);
    }
#pragma unroll
    for (int i = 0; i < 2; ++i) {
      int t = wave * 2 + i;
      int row = t * 8 + grow;
      gload16(bt2 + ((size_t)(g * 4 + slab) * 512 + n0 + row) * 512 + off + gcol,
              Bs + t * 512);
    }
    __syncthreads();
#pragma unroll
    for (int kk = 0; kk < 2; ++kk) {
      const int col = (kk * 32 + lk) ^ rmask;
      bf16x8 af[4], bfr[2];
#pragma unroll
      for (int i = 0; i < 4; ++i)
        af[i] = *(const bf16x8*)(As + (wr + i * 16 + lr) * 64 + col);
#pragma unroll
      for (int j = 0; j < 2; ++j)
        bfr[j] = *(const bf16x8*)(Bs + (wc + j * 16 + lr) * 64 + col);
#pragma unroll
      for (int i = 0; i < 4; ++i)
#pragma unroll
        for (int j = 0; j < 2; ++j)
          acc[i][j] = MFMA(af[i], bfr[j], acc[i][j]);
    }
    __syncthreads();
  }
#pragma unroll
  for (int j = 0; j < 2; ++j) {
    int gn = n0 + wc + j * 16 + lr;
#pragma unroll
    for (int i = 0; i < 4; ++i) {
#pragma unroll
      for (int q = 0; q < 4; ++q) {
        int gm = m0 + wr + i * 16 + frow + q;
        size_t idx = (size_t)gm * 512 + gn;
        if (MODE == 0)
          o1acc[idx] = acc[i][j][q];
        else
          o1b[idx] = (bf16_t)(acc[i][j][q] + o1acc[idx] + cvec[gn]);
      }
    }
  }
}

// ---------------------------------------------------------------- head (split-K 256)
__global__ __launch_bounds__(256) void k_head_partial(const bf16_t* __restrict__ Z,
                                                      const bf16_t* __restrict__ WhT,
                                                      float* __restrict__ part) {
  __shared__ __align__(16) bf16_t As[64 * 68];
  __shared__ __align__(16) bf16_t Bs[96 * 68];
  const int tid = threadIdx.x, lane = tid & 63, wave = tid >> 6;
  const int wr = (wave >> 1) * 32, wc = (wave & 1) * 48;
  const int lr = lane & 15, lk = (lane >> 4) * 8, frow = (lane >> 4) * 4;
  const int k0 = blockIdx.x * 256;
  const int sr = tid >> 3, sc = (tid & 7) * 8;
  f32x4 acc[2][3] = {};
  for (int kt = 0; kt < 256; kt += 64) {
#pragma unroll
    for (int i = 0; i < 2; ++i) {
      int r = i * 32 + sr;
      *(bf16x8*)(As + r * 68 + sc) = *(const bf16x8*)(Z + (size_t)r * 65536 + k0 + kt + sc);
    }
#pragma unroll
    for (int i = 0; i < 3; ++i) {
      int r = i * 32 + sr;
      *(bf16x8*)(Bs + r * 68 + sc) = *(const bf16x8*)(WhT + (size_t)r * 65536 + k0 + kt + sc);
    }
    __syncthreads();
#pragma unroll
    for (int kk = 0; kk < 2; ++kk) {
      bf16x8 af[2], bfr[3];
#pragma unroll
      for (int i = 0; i < 2; ++i)
        af[i] = *(const bf16x8*)(As + (wr + i * 16 + lr) * 68 + kk * 32 + lk);
#pragma unroll
      for (int j = 0; j < 3; ++j)
        bfr[j] = *(const bf16x8*)(Bs + (wc + j * 16 + lr) * 68 + kk * 32 + lk);
#pragma unroll
      for (int i = 0; i < 2; ++i)
#pragma unroll
        for (int j = 0; j < 3; ++j)
          acc[i][j] = MFMA(af[i], bfr[j], acc[i][j]);
    }
    __syncthreads();
  }
#pragma unroll
  for (int i = 0; i < 2; ++i)
#pragma unroll
    for (int j = 0; j < 3; ++j)
#pragma unroll
      for (int q = 0; q < 4; ++q) {
        int m = wr + i * 16 + frow + q;
        int n = wc + j * 16 + lr;
        part[(size_t)blockIdx.x * 6144 + m * 96 + n] = acc[i][j][q];
      }
}

__global__ __launch_bounds__(256) void k_head_reduce(const float* __restrict__ part,
                                                     const float* __restrict__ bias,
                                                     float* __restrict__ out) {
  int idx = blockIdx.x * 256 + threadIdx.x;
  if (idx >= 6144) return;
  float s = bias[idx % 96];
  for (int kb = 0; kb < 256; ++kb) s += part[(size_t)kb * 6144 + idx];
  out[idx] = s;
}

__global__ void k_sentinel(float* out, int n, float val) {
  int i = blockIdx.x * 256 + threadIdx.x;
  if (i < n) out[i] = val;
}

// ---------------------------------------------------------------- launch
extern "C" void kernel_launch(void* const* d_in, const int* in_sizes, int n_in,
                              void* d_out, int out_size, void* d_ws, size_t ws_size,
                              hipStream_t stream) {
  const float* x    = (const float*)d_in[0];
  const float* prev = (const float*)d_in[1];
  const float* Wq = (const float*)d_in[2];   const float* bq = (const float*)d_in[3];
  const float* Wk = (const float*)d_in[4];   const float* bk = (const float*)d_in[5];
  const float* Wv = (const float*)d_in[6];   const float* bv = (const float*)d_in[7];
  const float* Wo = (const float*)d_in[8];   const float* bo = (const float*)d_in[9];
  const float* scale = (const float*)d_in[10];
  const float* Wi1 = (const float*)d_in[11]; const float* bi1 = (const float*)d_in[12];
  const float* Wi2 = (const float*)d_in[13]; const float* bi2 = (const float*)d_in[14];
  const float* Wt1 = (const float*)d_in[15]; const float* bt1w = (const float*)d_in[16];
  const float* Wt2 = (const float*)d_in[17]; const float* bt2w = (const float*)d_in[18];
  const float* Wh = (const float*)d_in[19];  const float* bh = (const float*)d_in[20];
  float* out = (float*)d_out;

  char* p = (char*)d_ws;
  auto carve = [&](size_t bytes) {
    char* r = p;
    p += (bytes + 255) & ~(size_t)255;
    return r;
  };
  bf16_t* xb    = (bf16_t*)carve((size_t)8192 * 512 * 2);
  bf16_t* xTo1b = (bf16_t*)carve((size_t)8192 * 512 * 2);
  float*  o1acc = (float*)carve((size_t)8192 * 512 * 4);
  bf16_t* bt1   = (bf16_t*)carve((size_t)4096 * 512 * 2);
  bf16_t* bt2   = (bf16_t*)carve((size_t)4096 * 512 * 2);
  bf16_t* W12b  = (bf16_t*)carve(16 * 512 * 2);
  float*  cb    = (float*)carve(8 * 4);
  float*  cvec  = (float*)carve(512 * 4);
  char*   arena = carve((size_t)8192 * 2048 * 2);
  bf16_t* TU    = (bf16_t*)arena;
  float*  cpart = (float*)arena;
  bf16_t* xT    = xTo1b;
  bf16_t* o1b   = xTo1b;
  float*  TallT = (float*)bt1;
  char* q2 = arena;
  auto carve2 = [&](size_t bytes) {
    char* r = q2;
    q2 += (bytes + 255) & ~(size_t)255;
    return r;
  };
  bf16_t* whT  = (bf16_t*)carve2((size_t)96 * 65536 * 2);
  bf16_t* wt1T = (bf16_t*)carve2((size_t)512 * 512 * 2);
  bf16_t* wt2T = (bf16_t*)carve2((size_t)512 * 512 * 2);
  bf16_t* wi1T = (bf16_t*)carve2((size_t)128 * 128 * 2);
  bf16_t* wi2T = (bf16_t*)carve2((size_t)128 * 128 * 2);
  float*  hp   = (float*)carve2((size_t)256 * 64 * 96 * 4);
  bf16_t* bufB = (bf16_t*)carve2((size_t)8192 * 512 * 2);

  if ((size_t)(p - (char*)d_ws) > ws_size) {
    k_sentinel<<<24, 256, 0, stream>>>(out, 6144, (float)ws_size);
    return;
  }

  dim3 blk(256);
  // ---- prep
  k_cvec1<<<32, blk, 0, stream>>>(bv, Wo, cpart);
  k_cvec2<<<2, blk, 0, stream>>>(cpart, bo, cvec);
  k_convert_dual<<<dim3(16, 256), blk, 0, stream>>>(x, xb, xT);
  k_wprod<0><<<dim3(4, 4, 8), blk, 0, stream>>>(Wq, Wk, bt1, 4096, 4096);
  k_wprod<1><<<dim3(4, 4, 8), blk, 0, stream>>>(Wv, Wo, bt2, 4096, 512);
  k_sbias2<<<128, blk, 0, stream>>>(Wq, bk, Wk, bq, W12b, cb);

  // ---- attention path, 2 head-groups (attn9 both — best measured variant)
  // g=0
  k_gemm<2, 0><<<dim3(64, 16), blk, 0, stream>>>(xb, bt1, nullptr, TU, 8192, 2048, 512);
  k_tbias2<<<128, blk, 0, stream>>>(xb, W12b, cb, TallT);
  k_attn9<<<2048, dim3(64), 0, stream>>>(xb, xT, TU, prev, scale, TallT, 0);
  k_gemm2n<0><<<dim3(64, 8), blk, 0, stream>>>(TU, bt2, o1acc, cvec, o1b, 0);
  // g=1
  k_gemm<2, 0><<<dim3(64, 16), blk, 0, stream>>>(xb, bt1 + (size_t)2048 * 512, nullptr, TU,
                                                 8192, 2048, 512);
  k_attn9<<<2048, dim3(64), 0, stream>>>(xb, xT, TU, prev, scale, TallT, 1);
  k_gemm2n<1><<<dim3(64, 8), blk, 0, stream>>>(TU, bt2, o1acc, cvec, o1b, 1);

  // ---- tail weight converts (arena now safe to overwrite)
  k_transpose_convert<<<dim3(4, 4), blk, 0, stream>>>(Wi1, wi1T, 128, 128);
  k_transpose_convert<<<dim3(4, 4), blk, 0, stream>>>(Wi2, wi2T, 128, 128);
  k_transpose_convert<<<dim3(16, 16), blk, 0, stream>>>(Wt1, wt1T, 512, 512);
  k_transpose_convert<<<dim3(16, 16), blk, 0, stream>>>(Wt2, wt2T, 512, 512);
  k_transpose_convert<<<dim3(3, 2048), blk, 0, stream>>>(Wh, whT, 65536, 96);

  // ---- InterPatchMixing: fused transposed GEMMs (no separate transposes)
  k_gemmT1<<<512, blk, 0, stream>>>(o1b, wi1T, bi1, bufB);
  k_gemmT2<<<512, blk, 0, stream>>>(bufB, wi2T, bi2, o1b);

  // ---- IntraPatchMixing (64-row tiles)
  k_gemm64<1><<<dim3(128, 4), blk, 0, stream>>>(o1b, wt1T, bt1w, bufB, 8192, 512, 512);
  k_gemm64<0><<<dim3(128, 4), blk, 0, stream>>>(bufB, wt2T, bt2w, o1b, 8192, 512, 512);

  // ---- Flatten head: split-K=256
  k_head_partial<<<256, blk, 0, stream>>>(o1b, whT, hp);
  k_head_reduce<<<24, blk, 0, stream>>>(hp, bh, out);
}